// Round 1
// baseline (353.420 us; speedup 1.0000x reference)
//
#include <hip/hip_runtime.h>
#include <hip/hip_bf16.h>
#include <stdint.h>

// 2-layer LSTM (H=64) fused over T=336, B=4096, + final linear->sigmoid.
// Mapping: per WG: 16 batch elements (N), 4 waves each owning j-slice [16w,16w+16)
// of all 4 gate types (M-tiles {w, w+4, w+8, w+12}).  Weights live in VGPR A-frags.
// c-state fp32 in regs; h exchanged via swizzled bf16 LDS.

typedef __attribute__((ext_vector_type(8))) short s16x8;
typedef __attribute__((ext_vector_type(4))) short s16x4;
typedef __attribute__((ext_vector_type(4))) float f32x4;

#define MFMA_BF16 __builtin_amdgcn_mfma_f32_16x16x32_bf16

__device__ __forceinline__ short f2bf(float f) {
    uint32_t u = __builtin_bit_cast(uint32_t, f);
    u += 0x7fffu + ((u >> 16) & 1u);   // round-to-nearest-even
    return (short)(u >> 16);
}

__device__ __forceinline__ float fsigm(float x) {
    float e = __builtin_amdgcn_exp2f(x * -1.4426950408889634f); // e^-x
    return __builtin_amdgcn_rcpf(1.0f + e);
}
__device__ __forceinline__ float ftanh(float x) {
    float e = __builtin_amdgcn_exp2f(x * 2.8853900817779268f);  // e^{2x}
    return 1.0f - 2.0f * __builtin_amdgcn_rcpf(1.0f + e);
}

__global__ __launch_bounds__(256, 1)
void lstm_fused(const float* __restrict__ x,
                const float* __restrict__ w_ih0, const float* __restrict__ w_hh0,
                const float* __restrict__ b_ih0, const float* __restrict__ b_hh0,
                const float* __restrict__ w_ih1, const float* __restrict__ w_hh1,
                const float* __restrict__ b_ih1, const float* __restrict__ b_hh1,
                const float* __restrict__ w_lin, const float* __restrict__ b_lin,
                float* __restrict__ out)
{
    // xs: [t=16][b=16][d=32] bf16, swizzled (short idx ^ ((b&3)<<3))  -> 16 KB
    // hc: [b=16][j=128] bf16 (cols 0:64 = h0, 64:128 = h1), swizzled ^((b&7)<<3) -> 4 KB
    __shared__ __align__(16) short xs[16 * 512];
    __shared__ __align__(16) short hc[16 * 128];
    __shared__ float red[4][16];

    const int tid  = threadIdx.x;
    const int w    = tid >> 6;       // wave 0..3
    const int l    = tid & 63;       // lane
    const int bcol = l & 15;         // batch col (N) for MFMA frags
    const int q    = l >> 4;         // lane quad 0..3
    const int b0   = blockIdx.x * 16;

    // ---- zero LDS (h starts at 0; x pad lanes stay 0 forever) ----
    for (int i = tid; i < 16 * 512; i += 256) xs[i] = 0;
    for (int i = tid; i < 16 * 128; i += 256) hc[i] = 0;
    __syncthreads();

    // ---- weight fragments (A: lane holds A[row=bcol][k = q*8 + r]) ----
    s16x8 aIn[4];        // W_ih0 (K padded 9->32)
    s16x8 aRec[4][2];    // W_hh0, kf=0..1
    s16x8 aL1[4][4];     // [W_ih1 | W_hh1], kf=0..3 (K=128)
    f32x4 bias0[4], bias1[4];

    #pragma unroll
    for (int m = 0; m < 4; ++m) {
        const int R = m * 64 + w * 16 + bcol;    // global gate row (i,f,g,o blocks)
        #pragma unroll
        for (int r = 0; r < 8; ++r) {
            int k = q * 8 + r;
            aIn[m][r] = (k < 9) ? f2bf(w_ih0[R * 9 + k]) : (short)0;
        }
        #pragma unroll
        for (int kf = 0; kf < 2; ++kf) {
            const float* p = w_hh0 + R * 64 + kf * 32 + q * 8;
            #pragma unroll
            for (int r = 0; r < 8; ++r) aRec[m][kf][r] = f2bf(p[r]);
        }
        #pragma unroll
        for (int kf = 0; kf < 4; ++kf) {
            int ks = kf * 32 + q * 8;
            const float* p = (ks < 64) ? (w_ih1 + R * 64 + ks)
                                       : (w_hh1 + R * 64 + (ks - 64));
            #pragma unroll
            for (int r = 0; r < 8; ++r) aL1[m][kf][r] = f2bf(p[r]);
        }
        #pragma unroll
        for (int r = 0; r < 4; ++r) {           // C layout: row = q*4 + r
            int G = m * 64 + w * 16 + q * 4 + r;
            bias0[m][r] = b_ih0[G] + b_hh0[G];
            bias1[m][r] = b_ih1[G] + b_hh1[G];
        }
    }

    f32x4 c0 = {0.f, 0.f, 0.f, 0.f}, c1 = {0.f, 0.f, 0.f, 0.f};
    f32x4 h1q = {0.f, 0.f, 0.f, 0.f};

    const int hswz       = (bcol & 7) << 3;
    const int hc_rd_base = bcol * 128;
    const int hc_wr0     = (bcol * 128 + w * 16 + q * 4) ^ hswz;
    const int hc_wr1     = (bcol * 128 + 64 + w * 16 + q * 4) ^ hswz;

    const int    ld_b = tid >> 4, ld_t = tid & 15;
    const float* xrow = x + (size_t)(b0 + ld_b) * (336 * 9);
    const int    xs_wr_base = ld_t * 512 + ld_b * 32;
    const int    xswzw = (ld_b & 3) << 3;
    const int    xs_rd = (bcol * 32 + q * 8);   // + t*512, ^ ((bcol&3)<<3)
    const int    xswzr = (bcol & 3) << 3;

    #pragma unroll 1
    for (int t = 0; t < 336; ++t) {
        if ((t & 15) == 0) {
            const float* xp = xrow + (size_t)(t + ld_t) * 9;
            #pragma unroll
            for (int d = 0; d < 9; ++d)
                xs[(xs_wr_base + d) ^ xswzw] = f2bf(xp[d]);
            __syncthreads();
        }
        const int tin = t & 15;

        // ---- phase A: read all B-frags that depend on previous state ----
        s16x8 bx   = *(const s16x8*)&xs[((tin * 512 + xs_rd) ^ xswzr)];
        s16x8 bh0a = *(const s16x8*)&hc[(hc_rd_base + 0 * 32 + q * 8) ^ hswz];
        s16x8 bh0b = *(const s16x8*)&hc[(hc_rd_base + 1 * 32 + q * 8) ^ hswz];
        s16x8 bh1a = *(const s16x8*)&hc[(hc_rd_base + 2 * 32 + q * 8) ^ hswz]; // h1_prev
        s16x8 bh1b = *(const s16x8*)&hc[(hc_rd_base + 3 * 32 + q * 8) ^ hswz];

        // ---- layer 0: gates = bias + x@Wih^T + h0@Whh^T ----
        f32x4 acc[4];
        #pragma unroll
        for (int m = 0; m < 4; ++m) acc[m] = MFMA_BF16(aIn[m],     bx,   bias0[m], 0, 0, 0);
        #pragma unroll
        for (int m = 0; m < 4; ++m) acc[m] = MFMA_BF16(aRec[m][0], bh0a, acc[m],   0, 0, 0);
        #pragma unroll
        for (int m = 0; m < 4; ++m) acc[m] = MFMA_BF16(aRec[m][1], bh0b, acc[m],   0, 0, 0);

        f32x4 h0q;
        #pragma unroll
        for (int r = 0; r < 4; ++r) {
            float iv = fsigm(acc[0][r]);
            float fv = fsigm(acc[1][r]);
            float gv = ftanh(acc[2][r]);
            float ov = fsigm(acc[3][r]);
            float cc = fv * c0[r] + iv * gv;
            c0[r] = cc;
            h0q[r] = ov * ftanh(cc);
        }

        __syncthreads();   // all phase-A reads of h0_prev done
        { s16x4 p = { f2bf(h0q[0]), f2bf(h0q[1]), f2bf(h0q[2]), f2bf(h0q[3]) };
          *(s16x4*)&hc[hc_wr0] = p; }
        __syncthreads();   // h0_t visible

        s16x8 bh0n0 = *(const s16x8*)&hc[(hc_rd_base + 0 * 32 + q * 8) ^ hswz];
        s16x8 bh0n1 = *(const s16x8*)&hc[(hc_rd_base + 1 * 32 + q * 8) ^ hswz];

        // ---- layer 1: gates = bias + h0_t@Wih1^T + h1_prev@Whh1^T (K=128) ----
        #pragma unroll
        for (int m = 0; m < 4; ++m) acc[m] = MFMA_BF16(aL1[m][0], bh0n0, bias1[m], 0, 0, 0);
        #pragma unroll
        for (int m = 0; m < 4; ++m) acc[m] = MFMA_BF16(aL1[m][1], bh0n1, acc[m],   0, 0, 0);
        #pragma unroll
        for (int m = 0; m < 4; ++m) acc[m] = MFMA_BF16(aL1[m][2], bh1a,  acc[m],   0, 0, 0);
        #pragma unroll
        for (int m = 0; m < 4; ++m) acc[m] = MFMA_BF16(aL1[m][3], bh1b,  acc[m],   0, 0, 0);

        #pragma unroll
        for (int r = 0; r < 4; ++r) {
            float iv = fsigm(acc[0][r]);
            float fv = fsigm(acc[1][r]);
            float gv = ftanh(acc[2][r]);
            float ov = fsigm(acc[3][r]);
            float cc = fv * c1[r] + iv * gv;
            c1[r] = cc;
            h1q[r] = ov * ftanh(cc);
        }

        __syncthreads();   // phase-A reads of h1_prev long done (two barriers ago)
        { s16x4 p = { f2bf(h1q[0]), f2bf(h1q[1]), f2bf(h1q[2]), f2bf(h1q[3]) };
          *(s16x4*)&hc[hc_wr1] = p; }
        __syncthreads();   // h1_t visible for next step
    }

    // ---- final linear + sigmoid: out[b] = sigm(sum_j h1[b][j]*w_lin[j] + b_lin) ----
    float wl0 = w_lin[w * 16 + q * 4 + 0];
    float wl1 = w_lin[w * 16 + q * 4 + 1];
    float wl2 = w_lin[w * 16 + q * 4 + 2];
    float wl3 = w_lin[w * 16 + q * 4 + 3];
    float part = h1q[0] * wl0 + h1q[1] * wl1 + h1q[2] * wl2 + h1q[3] * wl3;
    part += __shfl_xor(part, 16, 64);
    part += __shfl_xor(part, 32, 64);
    if (q == 0) red[w][bcol] = part;
    __syncthreads();
    if (tid < 16) {
        float s = red[0][tid] + red[1][tid] + red[2][tid] + red[3][tid] + b_lin[0];
        out[b0 + tid] = fsigm(s);
    }
}

extern "C" void kernel_launch(void* const* d_in, const int* in_sizes, int n_in,
                              void* d_out, int out_size, void* d_ws, size_t ws_size,
                              hipStream_t stream) {
    const float* x     = (const float*)d_in[0];
    const float* w_ih0 = (const float*)d_in[1];
    const float* w_hh0 = (const float*)d_in[2];
    const float* b_ih0 = (const float*)d_in[3];
    const float* b_hh0 = (const float*)d_in[4];
    const float* w_ih1 = (const float*)d_in[5];
    const float* w_hh1 = (const float*)d_in[6];
    const float* b_ih1 = (const float*)d_in[7];
    const float* b_hh1 = (const float*)d_in[8];
    const float* w_lin = (const float*)d_in[9];
    const float* b_lin = (const float*)d_in[10];

    lstm_fused<<<dim3(256), dim3(256), 0, stream>>>(
        x, w_ih0, w_hh0, b_ih0, b_hh0,
        w_ih1, w_hh1, b_ih1, b_hh1,
        w_lin, b_lin, (float*)d_out);
}

// Round 2
// 306.384 us; speedup vs baseline: 1.1535x; 1.1535x over previous
//
#include <hip/hip_runtime.h>
#include <hip/hip_bf16.h>
#include <stdint.h>

// 2-layer LSTM (H=64) fused over T=336, B=4096, + final linear->sigmoid.
// Layer-pipelined: iteration i computes L0 step i (waves 0-3) and L1 step i-1
// (waves 4-7).  Both read only iteration-(i-1) state -> 2 barriers/step.
// Weights in VGPR A-frags; c fp32 in regs; h via swizzled bf16 LDS.

typedef __attribute__((ext_vector_type(8))) short s16x8;
typedef __attribute__((ext_vector_type(4))) short s16x4;
typedef __attribute__((ext_vector_type(4))) float f32x4;

#define MFMA_BF16 __builtin_amdgcn_mfma_f32_16x16x32_bf16

__device__ __forceinline__ short f2bf(float f) {
    uint32_t u = __builtin_bit_cast(uint32_t, f);
    u += 0x7fffu + ((u >> 16) & 1u);   // round-to-nearest-even
    return (short)(u >> 16);
}

__device__ __forceinline__ float fsigm(float x) {
    float e = __builtin_amdgcn_exp2f(x * -1.4426950408889634f); // e^-x
    return __builtin_amdgcn_rcpf(1.0f + e);
}
__device__ __forceinline__ float ftanh(float x) {
    float e = __builtin_amdgcn_exp2f(x * 2.8853900817779268f);  // e^{2x}
    return 1.0f - 2.0f * __builtin_amdgcn_rcpf(1.0f + e);
}

__global__ __launch_bounds__(512, 1)
void lstm_fused(const float* __restrict__ x,
                const float* __restrict__ w_ih0, const float* __restrict__ w_hh0,
                const float* __restrict__ b_ih0, const float* __restrict__ b_hh0,
                const float* __restrict__ w_ih1, const float* __restrict__ w_hh1,
                const float* __restrict__ b_ih1, const float* __restrict__ b_hh1,
                const float* __restrict__ w_lin, const float* __restrict__ b_lin,
                float* __restrict__ out)
{
    // xs: [t=16][b=16][d=32] bf16, swizzled (short idx ^ ((b&3)<<3))  -> 16 KB
    // h0s/h1s: [b=16][j=64] bf16, 16B-slot swizzle slot^=(b&7)        -> 2 KB each
    __shared__ __align__(16) short xs[16 * 512];
    __shared__ __align__(16) short h0s[16 * 64];
    __shared__ __align__(16) short h1s[16 * 64];
    __shared__ float red[4][16];

    const int tid  = threadIdx.x;
    const int w    = tid >> 6;       // wave 0..7
    const int role = w >> 2;         // 0 = layer0, 1 = layer1
    const int wl   = w & 3;          // wave-within-role: j-slice [16wl,16wl+16)
    const int l    = tid & 63;
    const int bcol = l & 15;         // batch col (MFMA N / B-frag col / A-frag row)
    const int q    = l >> 4;         // lane quad
    const int b0   = blockIdx.x * 16;

    for (int i = tid; i < 16 * 512; i += 512) xs[i] = 0;
    for (int i = tid; i < 16 * 64; i += 512) { h0s[i] = 0; h1s[i] = 0; }
    __syncthreads();

    // ---- weight A-frags: lane holds A[row=bcol][k = q*8 + r] ----
    // role0: kf0 = W_ih0 (K 9->32 pad), kf1/kf2 = W_hh0.  role1: kf0..3 = [W_ih1|W_hh1]
    s16x8 aW[4][4];
    f32x4 bias[4];
    #pragma unroll
    for (int m = 0; m < 4; ++m) {
        const int R = m * 64 + wl * 16 + bcol;
        if (role == 0) {
            #pragma unroll
            for (int r = 0; r < 8; ++r) {
                int k = q * 8 + r;
                aW[m][0][r] = (k < 9) ? f2bf(w_ih0[R * 9 + k]) : (short)0;
            }
            #pragma unroll
            for (int kf = 0; kf < 2; ++kf) {
                const float* p = w_hh0 + R * 64 + kf * 32 + q * 8;
                #pragma unroll
                for (int r = 0; r < 8; ++r) aW[m][1 + kf][r] = f2bf(p[r]);
            }
            #pragma unroll
            for (int r = 0; r < 8; ++r) aW[m][3][r] = 0;
            #pragma unroll
            for (int r = 0; r < 4; ++r) {
                int G = m * 64 + wl * 16 + q * 4 + r;
                bias[m][r] = b_ih0[G] + b_hh0[G];
            }
        } else {
            #pragma unroll
            for (int kf = 0; kf < 4; ++kf) {
                int ks = kf * 32 + q * 8;
                const float* p = (ks < 64) ? (w_ih1 + R * 64 + ks)
                                           : (w_hh1 + R * 64 + (ks - 64));
                #pragma unroll
                for (int r = 0; r < 8; ++r) aW[m][kf][r] = f2bf(p[r]);
            }
            #pragma unroll
            for (int r = 0; r < 4; ++r) {
                int G = m * 64 + wl * 16 + q * 4 + r;
                bias[m][r] = b_ih1[G] + b_hh1[G];
            }
        }
    }

    f32x4 c = {0.f, 0.f, 0.f, 0.f};      // cell state (per role)
    f32x4 hq = {0.f, 0.f, 0.f, 0.f};     // last h quad (role1 keeps h1_335)

    // h LDS addressing (shorts): elem (b, j) at b*64 + ((j>>3)^(b&7))*8 + (j&7)
    const int hrd0 = bcol * 64 + (((q    ) ^ (bcol & 7)) << 3);          // j = q*8..
    const int hrd1 = bcol * 64 + (((4 + q) ^ (bcol & 7)) << 3);          // j = 32+q*8..
    const int hwr  = bcol * 64 + (((wl * 2 + (q >> 1)) ^ (bcol & 7)) << 3)
                   + ((q & 1) << 2);                                     // j = wl*16+q*4
    const int xrd  = bcol * 32 + ((q ^ (bcol & 3)) << 3);

    const int    ld_b = (tid & 255) >> 4, ld_t = tid & 15;
    const float* xrow = x + (size_t)(b0 + ld_b) * (336 * 9) + ld_t * 9;
    const int    xs_wr_base = ld_t * 512 + ld_b * 32;
    const int    xswzw = (ld_b & 3) << 3;

    #pragma unroll 1
    for (int i = 0; i <= 336; ++i) {
        if ((i & 15) == 0 && i < 336) {
            if (tid < 256) {
                const float* xp = xrow + (size_t)i * 9;
                #pragma unroll
                for (int d = 0; d < 9; ++d)
                    xs[(xs_wr_base + d) ^ xswzw] = f2bf(xp[d]);
            }
            __syncthreads();
        }

        const bool act0 = (role == 0) & (i < 336);
        const bool act1 = (role == 1) & (i > 0);

        s16x4 pv;
        bool wrote = false;
        if (act0) {
            // L0 step i: gates = bias + x_i@Wih0^T + h0_{i-1}@Whh0^T
            s16x8 bx  = *(const s16x8*)&xs[(i & 15) * 512 + xrd];
            s16x8 ba  = *(const s16x8*)&h0s[hrd0];
            s16x8 bb  = *(const s16x8*)&h0s[hrd1];
            f32x4 acc[4];
            #pragma unroll
            for (int m = 0; m < 4; ++m) acc[m] = MFMA_BF16(aW[m][0], bx, bias[m], 0, 0, 0);
            #pragma unroll
            for (int m = 0; m < 4; ++m) acc[m] = MFMA_BF16(aW[m][1], ba, acc[m], 0, 0, 0);
            #pragma unroll
            for (int m = 0; m < 4; ++m) acc[m] = MFMA_BF16(aW[m][2], bb, acc[m], 0, 0, 0);
            #pragma unroll
            for (int r = 0; r < 4; ++r) {
                float iv = fsigm(acc[0][r]);
                float fv = fsigm(acc[1][r]);
                float gv = ftanh(acc[2][r]);
                float ov = fsigm(acc[3][r]);
                float cc = fv * c[r] + iv * gv;
                c[r] = cc;
                hq[r] = ov * ftanh(cc);
            }
            pv = (s16x4){ f2bf(hq[0]), f2bf(hq[1]), f2bf(hq[2]), f2bf(hq[3]) };
            wrote = true;
        } else if (act1) {
            // L1 step i-1: gates = bias + h0_{i-1}@Wih1^T + h1_{i-2}@Whh1^T
            s16x8 ba  = *(const s16x8*)&h0s[hrd0];
            s16x8 bb  = *(const s16x8*)&h0s[hrd1];
            s16x8 b1a = *(const s16x8*)&h1s[hrd0];
            s16x8 b1b = *(const s16x8*)&h1s[hrd1];
            f32x4 acc[4];
            #pragma unroll
            for (int m = 0; m < 4; ++m) acc[m] = MFMA_BF16(aW[m][0], ba,  bias[m], 0, 0, 0);
            #pragma unroll
            for (int m = 0; m < 4; ++m) acc[m] = MFMA_BF16(aW[m][1], bb,  acc[m], 0, 0, 0);
            #pragma unroll
            for (int m = 0; m < 4; ++m) acc[m] = MFMA_BF16(aW[m][2], b1a, acc[m], 0, 0, 0);
            #pragma unroll
            for (int m = 0; m < 4; ++m) acc[m] = MFMA_BF16(aW[m][3], b1b, acc[m], 0, 0, 0);
            #pragma unroll
            for (int r = 0; r < 4; ++r) {
                float iv = fsigm(acc[0][r]);
                float fv = fsigm(acc[1][r]);
                float gv = ftanh(acc[2][r]);
                float ov = fsigm(acc[3][r]);
                float cc = fv * c[r] + iv * gv;
                c[r] = cc;
                hq[r] = ov * ftanh(cc);
            }
            pv = (s16x4){ f2bf(hq[0]), f2bf(hq[1]), f2bf(hq[2]), f2bf(hq[3]) };
            wrote = true;
        }

        __syncthreads();   // all iteration-i reads of h0/h1 complete
        if (wrote) {
            if (role == 0) *(s16x4*)&h0s[hwr] = pv;
            else           *(s16x4*)&h1s[hwr] = pv;
        }
        __syncthreads();   // new h0_i / h1_{i-1} visible
    }

    // ---- out[b] = sigm(sum_j h1_335[b][j] * w_lin[j] + b_lin) ----
    if (role == 1) {
        float part = hq[0] * w_lin[wl * 16 + q * 4 + 0]
                   + hq[1] * w_lin[wl * 16 + q * 4 + 1]
                   + hq[2] * w_lin[wl * 16 + q * 4 + 2]
                   + hq[3] * w_lin[wl * 16 + q * 4 + 3];
        part += __shfl_xor(part, 16, 64);
        part += __shfl_xor(part, 32, 64);
        if (q == 0) red[wl][bcol] = part;
    }
    __syncthreads();
    if (tid < 16) {
        float s = red[0][tid] + red[1][tid] + red[2][tid] + red[3][tid] + b_lin[0];
        out[b0 + tid] = fsigm(s);
    }
}

extern "C" void kernel_launch(void* const* d_in, const int* in_sizes, int n_in,
                              void* d_out, int out_size, void* d_ws, size_t ws_size,
                              hipStream_t stream) {
    const float* x     = (const float*)d_in[0];
    const float* w_ih0 = (const float*)d_in[1];
    const float* w_hh0 = (const float*)d_in[2];
    const float* b_ih0 = (const float*)d_in[3];
    const float* b_hh0 = (const float*)d_in[4];
    const float* w_ih1 = (const float*)d_in[5];
    const float* w_hh1 = (const float*)d_in[6];
    const float* b_ih1 = (const float*)d_in[7];
    const float* b_hh1 = (const float*)d_in[8];
    const float* w_lin = (const float*)d_in[9];
    const float* b_lin = (const float*)d_in[10];

    lstm_fused<<<dim3(256), dim3(512), 0, stream>>>(
        x, w_ih0, w_hh0, b_ih0, b_hh0,
        w_ih1, w_hh1, b_ih1, b_hh1,
        w_lin, b_lin, (float*)d_out);
}

// Round 3
// 306.053 us; speedup vs baseline: 1.1548x; 1.0011x over previous
//
#include <hip/hip_runtime.h>
#include <hip/hip_bf16.h>
#include <stdint.h>

// 2-layer LSTM (H=64) fused over T=336, B=4096, + final linear->sigmoid.
// Layer-pipelined: iteration i computes L0 step i (waves 0-3) and L1 step i-1
// (waves 4-7); both read only iteration-(i-1) state.  h-state DOUBLE-BUFFERED
// in LDS -> ONE barrier per iteration (WAR removed by buffer swap, RAW by the
// end-of-iter barrier).  Weights in VGPR A-frags; c fp32 in regs.

typedef __attribute__((ext_vector_type(8))) short s16x8;
typedef __attribute__((ext_vector_type(4))) short s16x4;
typedef __attribute__((ext_vector_type(4))) float f32x4;

#define MFMA_BF16 __builtin_amdgcn_mfma_f32_16x16x32_bf16

__device__ __forceinline__ short f2bf(float f) {
    uint32_t u = __builtin_bit_cast(uint32_t, f);
    u += 0x7fffu + ((u >> 16) & 1u);   // round-to-nearest-even
    return (short)(u >> 16);
}

// 4x f32 -> 4x bf16 via v_cvt_pk_bf16_f32 (dst.lo = src0, dst.hi = src1)
__device__ __forceinline__ s16x4 pack_bf16x4(float a, float b, float c, float d) {
    union { uint32_t u[2]; s16x4 s; } r;
    asm("v_cvt_pk_bf16_f32 %0, %1, %2" : "=v"(r.u[0]) : "v"(a), "v"(b));
    asm("v_cvt_pk_bf16_f32 %0, %1, %2" : "=v"(r.u[1]) : "v"(c), "v"(d));
    return r.s;
}

__device__ __forceinline__ float fsigm(float x) {
    float e = __builtin_amdgcn_exp2f(x * -1.4426950408889634f); // e^-x
    return __builtin_amdgcn_rcpf(1.0f + e);
}
__device__ __forceinline__ float ftanh(float x) {
    float e = __builtin_amdgcn_exp2f(x * 2.8853900817779268f);  // e^{2x}
    return 1.0f - 2.0f * __builtin_amdgcn_rcpf(1.0f + e);
}

__global__ __launch_bounds__(512, 1)
void lstm_fused(const float* __restrict__ x,
                const float* __restrict__ w_ih0, const float* __restrict__ w_hh0,
                const float* __restrict__ b_ih0, const float* __restrict__ b_hh0,
                const float* __restrict__ w_ih1, const float* __restrict__ w_hh1,
                const float* __restrict__ b_ih1, const float* __restrict__ b_hh1,
                const float* __restrict__ w_lin, const float* __restrict__ b_lin,
                float* __restrict__ out)
{
    // xs: [t=16][b=16][d=32] bf16, swizzled (short idx ^ ((b&3)<<3))  -> 16 KB
    // h0s/h1s: [2][b=16][j=64] bf16, 16B-slot swizzle slot^=(b&7)     -> 4 KB each
    __shared__ __align__(16) short xs[16 * 512];
    __shared__ __align__(16) short h0s[2][16 * 64];
    __shared__ __align__(16) short h1s[2][16 * 64];
    __shared__ float red[4][16];

    const int tid  = threadIdx.x;
    const int w    = tid >> 6;       // wave 0..7
    const int role = w >> 2;         // 0 = layer0, 1 = layer1
    const int wl   = w & 3;          // wave-within-role: j-slice [16wl,16wl+16)
    const int l    = tid & 63;
    const int bcol = l & 15;         // batch col (MFMA N / B-frag col / A-frag row)
    const int q    = l >> 4;         // lane quad
    const int b0   = blockIdx.x * 16;

    for (int i = tid; i < 16 * 512; i += 512) xs[i] = 0;
    for (int i = tid; i < 16 * 64; i += 512) {
        h0s[0][i] = 0; h0s[1][i] = 0; h1s[0][i] = 0; h1s[1][i] = 0;
    }
    __syncthreads();

    // ---- weight A-frags: lane holds A[row=bcol][k = q*8 + r] ----
    // role0: kf0 = W_ih0 (K 9->32 pad), kf1/kf2 = W_hh0.  role1: kf0..3 = [W_ih1|W_hh1]
    s16x8 aW[4][4];
    f32x4 bias[4];
    #pragma unroll
    for (int m = 0; m < 4; ++m) {
        const int R = m * 64 + wl * 16 + bcol;
        if (role == 0) {
            #pragma unroll
            for (int r = 0; r < 8; ++r) {
                int k = q * 8 + r;
                aW[m][0][r] = (k < 9) ? f2bf(w_ih0[R * 9 + k]) : (short)0;
            }
            #pragma unroll
            for (int kf = 0; kf < 2; ++kf) {
                const float* p = w_hh0 + R * 64 + kf * 32 + q * 8;
                #pragma unroll
                for (int r = 0; r < 8; ++r) aW[m][1 + kf][r] = f2bf(p[r]);
            }
            #pragma unroll
            for (int r = 0; r < 8; ++r) aW[m][3][r] = 0;
            #pragma unroll
            for (int r = 0; r < 4; ++r) {
                int G = m * 64 + wl * 16 + q * 4 + r;
                bias[m][r] = b_ih0[G] + b_hh0[G];
            }
        } else {
            #pragma unroll
            for (int kf = 0; kf < 4; ++kf) {
                int ks = kf * 32 + q * 8;
                const float* p = (ks < 64) ? (w_ih1 + R * 64 + ks)
                                           : (w_hh1 + R * 64 + (ks - 64));
                #pragma unroll
                for (int r = 0; r < 8; ++r) aW[m][kf][r] = f2bf(p[r]);
            }
            #pragma unroll
            for (int r = 0; r < 4; ++r) {
                int G = m * 64 + wl * 16 + q * 4 + r;
                bias[m][r] = b_ih1[G] + b_hh1[G];
            }
        }
    }

    f32x4 c = {0.f, 0.f, 0.f, 0.f};      // cell state (per role)
    f32x4 hq = {0.f, 0.f, 0.f, 0.f};     // last h quad (role1 keeps h1_335)

    // h LDS addressing (shorts): elem (b, j) at b*64 + ((j>>3)^(b&7))*8 + (j&7)
    const int hrd0 = bcol * 64 + (((q    ) ^ (bcol & 7)) << 3);          // j = q*8..
    const int hrd1 = bcol * 64 + (((4 + q) ^ (bcol & 7)) << 3);          // j = 32+q*8..
    const int hwr  = bcol * 64 + (((wl * 2 + (q >> 1)) ^ (bcol & 7)) << 3)
                   + ((q & 1) << 2);                                     // j = wl*16+q*4
    const int xrd  = bcol * 32 + ((q ^ (bcol & 3)) << 3);

    const int    ld_b = (tid & 255) >> 4, ld_t = tid & 15;
    const float* xrow = x + (size_t)(b0 + ld_b) * (336 * 9) + ld_t * 9;
    const int    xs_wr_base = ld_t * 512 + ld_b * 32;
    const int    xswzw = (ld_b & 3) << 3;

    #pragma unroll 1
    for (int i = 0; i <= 336; ++i) {
        if ((i & 15) == 0 && i < 336) {
            if (tid < 256) {
                const float* xp = xrow + (size_t)i * 9;
                #pragma unroll
                for (int d = 0; d < 9; ++d)
                    xs[(xs_wr_base + d) ^ xswzw] = f2bf(xp[d]);
            }
            __syncthreads();
        }

        const short* h0r = h0s[(i & 1) ^ 1];   // state from iteration i-1
        const short* h1r = h1s[(i & 1) ^ 1];
        short*       h0w = h0s[i & 1];
        short*       h1w = h1s[i & 1];

        const bool act0 = (role == 0) & (i < 336);
        const bool act1 = (role == 1) & (i > 0);

        if (act0) {
            // L0 step i: gates = bias + x_i@Wih0^T + h0_{i-1}@Whh0^T
            s16x8 bx = *(const s16x8*)&xs[(i & 15) * 512 + xrd];
            s16x8 ba = *(const s16x8*)&h0r[hrd0];
            s16x8 bb = *(const s16x8*)&h0r[hrd1];
            f32x4 acc[4];
            #pragma unroll
            for (int m = 0; m < 4; ++m) acc[m] = MFMA_BF16(aW[m][0], bx, bias[m], 0, 0, 0);
            #pragma unroll
            for (int m = 0; m < 4; ++m) acc[m] = MFMA_BF16(aW[m][1], ba, acc[m], 0, 0, 0);
            #pragma unroll
            for (int m = 0; m < 4; ++m) acc[m] = MFMA_BF16(aW[m][2], bb, acc[m], 0, 0, 0);
            #pragma unroll
            for (int r = 0; r < 4; ++r) {
                float iv = fsigm(acc[0][r]);
                float fv = fsigm(acc[1][r]);
                float gv = ftanh(acc[2][r]);
                float ov = fsigm(acc[3][r]);
                float cc = fv * c[r] + iv * gv;
                c[r] = cc;
                hq[r] = ov * ftanh(cc);
            }
            *(s16x4*)&h0w[hwr] = pack_bf16x4(hq[0], hq[1], hq[2], hq[3]);
        } else if (act1) {
            // L1 step i-1: gates = bias + h0_{i-1}@Wih1^T + h1_{i-2}@Whh1^T
            s16x8 ba  = *(const s16x8*)&h0r[hrd0];
            s16x8 bb  = *(const s16x8*)&h0r[hrd1];
            s16x8 b1a = *(const s16x8*)&h1r[hrd0];
            s16x8 b1b = *(const s16x8*)&h1r[hrd1];
            f32x4 acc[4];
            #pragma unroll
            for (int m = 0; m < 4; ++m) acc[m] = MFMA_BF16(aW[m][0], ba,  bias[m], 0, 0, 0);
            #pragma unroll
            for (int m = 0; m < 4; ++m) acc[m] = MFMA_BF16(aW[m][1], bb,  acc[m], 0, 0, 0);
            #pragma unroll
            for (int m = 0; m < 4; ++m) acc[m] = MFMA_BF16(aW[m][2], b1a, acc[m], 0, 0, 0);
            #pragma unroll
            for (int m = 0; m < 4; ++m) acc[m] = MFMA_BF16(aW[m][3], b1b, acc[m], 0, 0, 0);
            #pragma unroll
            for (int r = 0; r < 4; ++r) {
                float iv = fsigm(acc[0][r]);
                float fv = fsigm(acc[1][r]);
                float gv = ftanh(acc[2][r]);
                float ov = fsigm(acc[3][r]);
                float cc = fv * c[r] + iv * gv;
                c[r] = cc;
                hq[r] = ov * ftanh(cc);
            }
            *(s16x4*)&h1w[hwr] = pack_bf16x4(hq[0], hq[1], hq[2], hq[3]);
        }

        __syncthreads();   // h0_i / h1_{i-1} visible; also fences next iter's
                           // writes (into the buffer read this iter) behind us
    }

    // ---- out[b] = sigm(sum_j h1_335[b][j] * w_lin[j] + b_lin) ----
    if (role == 1) {
        float part = hq[0] * w_lin[wl * 16 + q * 4 + 0]
                   + hq[1] * w_lin[wl * 16 + q * 4 + 1]
                   + hq[2] * w_lin[wl * 16 + q * 4 + 2]
                   + hq[3] * w_lin[wl * 16 + q * 4 + 3];
        part += __shfl_xor(part, 16, 64);
        part += __shfl_xor(part, 32, 64);
        if (q == 0) red[wl][bcol] = part;
    }
    __syncthreads();
    if (tid < 16) {
        float s = red[0][tid] + red[1][tid] + red[2][tid] + red[3][tid] + b_lin[0];
        out[b0 + tid] = fsigm(s);
    }
}

extern "C" void kernel_launch(void* const* d_in, const int* in_sizes, int n_in,
                              void* d_out, int out_size, void* d_ws, size_t ws_size,
                              hipStream_t stream) {
    const float* x     = (const float*)d_in[0];
    const float* w_ih0 = (const float*)d_in[1];
    const float* w_hh0 = (const float*)d_in[2];
    const float* b_ih0 = (const float*)d_in[3];
    const float* b_hh0 = (const float*)d_in[4];
    const float* w_ih1 = (const float*)d_in[5];
    const float* w_hh1 = (const float*)d_in[6];
    const float* b_ih1 = (const float*)d_in[7];
    const float* b_hh1 = (const float*)d_in[8];
    const float* w_lin = (const float*)d_in[9];
    const float* b_lin = (const float*)d_in[10];

    lstm_fused<<<dim3(256), dim3(512), 0, stream>>>(
        x, w_ih0, w_hh0, b_ih0, b_hh0,
        w_ih1, w_hh1, b_ih1, b_hh1,
        w_lin, b_lin, (float*)d_out);
}

// Round 4
// 301.162 us; speedup vs baseline: 1.1735x; 1.0162x over previous
//
#include <hip/hip_runtime.h>
#include <hip/hip_bf16.h>
#include <stdint.h>

// 2-layer LSTM (H=64) fused over T=336, B=4096, + final linear->sigmoid.
// ANTIPHASE schedule: each iteration has two intervals (2 barriers).
//   A:  L0-waves: MFMA(gates0(i));          L1-waves: nonlin->h1(i-2), write
//   B:  L0-waves: nonlin->h0(i), write;     L1-waves: MFMA(gates1(i-1))
// So on every SIMD one wave is in its MFMA burst while the other is in its
// VALU burst -> MFMA and VALU pipes overlap instead of serializing.
// gates1 carried in regs across the barrier; h1 single-buffered, h0 double.
// exp-scales folded into weights: sigma = rcp(1+exp2(pre)).

typedef __attribute__((ext_vector_type(8))) short s16x8;
typedef __attribute__((ext_vector_type(4))) short s16x4;
typedef __attribute__((ext_vector_type(4))) float f32x4;

#define MFMA_BF16 __builtin_amdgcn_mfma_f32_16x16x32_bf16
#define LOG2E     1.4426950408889634f
#define TWO_LOG2E 2.8853900817779268f

__device__ __forceinline__ short f2bf(float f) {
    uint32_t u = __builtin_bit_cast(uint32_t, f);
    u += 0x7fffu + ((u >> 16) & 1u);   // round-to-nearest-even
    return (short)(u >> 16);
}

__device__ __forceinline__ s16x4 pack_bf16x4(float a, float b, float c, float d) {
    union { uint32_t u[2]; s16x4 s; } r;
    asm("v_cvt_pk_bf16_f32 %0, %1, %2" : "=v"(r.u[0]) : "v"(a), "v"(b));
    asm("v_cvt_pk_bf16_f32 %0, %1, %2" : "=v"(r.u[1]) : "v"(c), "v"(d));
    return r.s;
}

// rcp(1 + 2^t):  sigma(x) with t = -x*log2e ; tanh building block with t = 2x*log2e
__device__ __forceinline__ float rcp1p2(float t) {
    return __builtin_amdgcn_rcpf(1.0f + __builtin_amdgcn_exp2f(t));
}

__global__ __launch_bounds__(512, 1)
void lstm_fused(const float* __restrict__ x,
                const float* __restrict__ w_ih0, const float* __restrict__ w_hh0,
                const float* __restrict__ b_ih0, const float* __restrict__ b_hh0,
                const float* __restrict__ w_ih1, const float* __restrict__ w_hh1,
                const float* __restrict__ b_ih1, const float* __restrict__ b_hh1,
                const float* __restrict__ w_lin, const float* __restrict__ b_lin,
                float* __restrict__ out)
{
    __shared__ __align__(16) short xs[16 * 512];        // 16 KB x-chunk
    __shared__ __align__(16) short h0s[2][16 * 64];     // h0 double buffer
    __shared__ __align__(16) short h1s[16 * 64];        // h1 single buffer
    __shared__ float red[4][16];

    const int tid  = threadIdx.x;
    const int w    = tid >> 6;       // wave 0..7
    const int role = w >> 2;         // 0 = layer0, 1 = layer1
    const int wl   = w & 3;          // j-slice [16wl, 16wl+16)
    const int l    = tid & 63;
    const int bcol = l & 15;
    const int q    = l >> 4;
    const int b0   = blockIdx.x * 16;

    for (int i = tid; i < 16 * 512; i += 512) xs[i] = 0;
    for (int i = tid; i < 16 * 64; i += 512) {
        h0s[0][i] = 0; h0s[1][i] = 0; h1s[i] = 0;
    }
    __syncthreads();

    // per-gate-row exp2 scale folded into weights + biases
    // gates i,f,o: sigma(x) = rcp(1+exp2(-x*log2e)); gate g: tanh(x)=1-2*rcp(1+exp2(2x*log2e))
    const float scm[4] = { -LOG2E, -LOG2E, TWO_LOG2E, -LOG2E };

    s16x8 aW[4][4];
    f32x4 bias[4];
    #pragma unroll
    for (int m = 0; m < 4; ++m) {
        const int R = m * 64 + wl * 16 + bcol;
        const float sc = scm[m];
        if (role == 0) {
            #pragma unroll
            for (int r = 0; r < 8; ++r) {
                int k = q * 8 + r;
                aW[m][0][r] = (k < 9) ? f2bf(w_ih0[R * 9 + k] * sc) : (short)0;
            }
            #pragma unroll
            for (int kf = 0; kf < 2; ++kf) {
                const float* p = w_hh0 + R * 64 + kf * 32 + q * 8;
                #pragma unroll
                for (int r = 0; r < 8; ++r) aW[m][1 + kf][r] = f2bf(p[r] * sc);
            }
            #pragma unroll
            for (int r = 0; r < 8; ++r) aW[m][3][r] = 0;
            #pragma unroll
            for (int r = 0; r < 4; ++r) {
                int G = m * 64 + wl * 16 + q * 4 + r;
                bias[m][r] = (b_ih0[G] + b_hh0[G]) * sc;
            }
        } else {
            #pragma unroll
            for (int kf = 0; kf < 4; ++kf) {
                int ks = kf * 32 + q * 8;
                const float* p = (ks < 64) ? (w_ih1 + R * 64 + ks)
                                           : (w_hh1 + R * 64 + (ks - 64));
                #pragma unroll
                for (int r = 0; r < 8; ++r) aW[m][kf][r] = f2bf(p[r] * sc);
            }
            #pragma unroll
            for (int r = 0; r < 4; ++r) {
                int G = m * 64 + wl * 16 + q * 4 + r;
                bias[m][r] = (b_ih1[G] + b_hh1[G]) * sc;
            }
        }
    }

    f32x4 c  = {0.f, 0.f, 0.f, 0.f};
    f32x4 hq = {0.f, 0.f, 0.f, 0.f};
    f32x4 accL1[4];                      // L1 pending gates (set in B, used next A)
    #pragma unroll
    for (int m = 0; m < 4; ++m) accL1[m] = (f32x4){0.f, 0.f, 0.f, 0.f};

    const int hrd0 = bcol * 64 + (((q    ) ^ (bcol & 7)) << 3);
    const int hrd1 = bcol * 64 + (((4 + q) ^ (bcol & 7)) << 3);
    const int hwr  = bcol * 64 + (((wl * 2 + (q >> 1)) ^ (bcol & 7)) << 3)
                   + ((q & 1) << 2);
    const int xrd  = bcol * 32 + ((q ^ (bcol & 3)) << 3);

    const int    ld_b = (tid & 255) >> 4, ld_t = tid & 15;
    const float* xrow = x + (size_t)(b0 + ld_b) * (336 * 9) + ld_t * 9;
    const int    xs_wr_base = ld_t * 512 + ld_b * 32;
    const int    xswzw = (ld_b & 3) << 3;

    #pragma unroll 1
    for (int i = 0; i <= 337; ++i) {
        if ((i & 15) == 0 && i < 336) {
            if (tid < 256) {
                const float* xp = xrow + (size_t)i * 9;
                #pragma unroll
                for (int d = 0; d < 9; ++d)
                    xs[(xs_wr_base + d) ^ xswzw] = f2bf(xp[d]);
            }
            __syncthreads();
        }

        // ================= interval A =================
        f32x4 acc0[4];
        if (role == 0) {
            if (i <= 335) {
                s16x8 bx = *(const s16x8*)&xs[(i & 15) * 512 + xrd];
                const short* h0r = h0s[(i & 1) ^ 1];            // h0(i-1)
                s16x8 ba = *(const s16x8*)&h0r[hrd0];
                s16x8 bb = *(const s16x8*)&h0r[hrd1];
                #pragma unroll
                for (int m = 0; m < 4; ++m) acc0[m] = MFMA_BF16(aW[m][0], bx, bias[m], 0, 0, 0);
                #pragma unroll
                for (int m = 0; m < 4; ++m) acc0[m] = MFMA_BF16(aW[m][1], ba, acc0[m], 0, 0, 0);
                #pragma unroll
                for (int m = 0; m < 4; ++m) acc0[m] = MFMA_BF16(aW[m][2], bb, acc0[m], 0, 0, 0);
            }
        } else {
            if (i >= 2) {   // nonlin on gates1(i-2) -> h1(i-2)
                #pragma unroll
                for (int r = 0; r < 4; ++r) {
                    float iv = rcp1p2(accL1[0][r]);
                    float fv = rcp1p2(accL1[1][r]);
                    float gv = fmaf(-2.f, rcp1p2(accL1[2][r]), 1.f);
                    float ov = rcp1p2(accL1[3][r]);
                    float cc = fv * c[r] + iv * gv;
                    c[r] = cc;
                    hq[r] = ov * fmaf(-2.f, rcp1p2(cc * TWO_LOG2E), 1.f);
                }
                *(s16x4*)&h1s[hwr] = pack_bf16x4(hq[0], hq[1], hq[2], hq[3]);
            }
        }
        __syncthreads();   // B_mid: h1(i-2) visible

        // ================= interval B =================
        if (role == 0) {
            if (i <= 335) {
                #pragma unroll
                for (int r = 0; r < 4; ++r) {
                    float iv = rcp1p2(acc0[0][r]);
                    float fv = rcp1p2(acc0[1][r]);
                    float gv = fmaf(-2.f, rcp1p2(acc0[2][r]), 1.f);
                    float ov = rcp1p2(acc0[3][r]);
                    float cc = fv * c[r] + iv * gv;
                    c[r] = cc;
                    hq[r] = ov * fmaf(-2.f, rcp1p2(cc * TWO_LOG2E), 1.f);
                }
                short* h0w = h0s[i & 1];                        // h0(i)
                *(s16x4*)&h0w[hwr] = pack_bf16x4(hq[0], hq[1], hq[2], hq[3]);
            }
        } else {
            if (i >= 1 && i <= 336) {   // gates1(i-1) from h0(i-1), h1(i-2)
                const short* h0r = h0s[(i & 1) ^ 1];            // h0(i-1)
                s16x8 ba  = *(const s16x8*)&h0r[hrd0];
                s16x8 bb  = *(const s16x8*)&h0r[hrd1];
                s16x8 b1a = *(const s16x8*)&h1s[hrd0];
                s16x8 b1b = *(const s16x8*)&h1s[hrd1];
                #pragma unroll
                for (int m = 0; m < 4; ++m) accL1[m] = MFMA_BF16(aW[m][0], ba,  bias[m], 0, 0, 0);
                #pragma unroll
                for (int m = 0; m < 4; ++m) accL1[m] = MFMA_BF16(aW[m][1], bb,  accL1[m], 0, 0, 0);
                #pragma unroll
                for (int m = 0; m < 4; ++m) accL1[m] = MFMA_BF16(aW[m][2], b1a, accL1[m], 0, 0, 0);
                #pragma unroll
                for (int m = 0; m < 4; ++m) accL1[m] = MFMA_BF16(aW[m][3], b1b, accL1[m], 0, 0, 0);
            }
        }
        __syncthreads();   // B_end: h0(i) visible
    }

    // ---- out[b] = sigm(sum_j h1_335[b][j] * w_lin[j] + b_lin) ----
    if (role == 1) {
        float part = hq[0] * w_lin[wl * 16 + q * 4 + 0]
                   + hq[1] * w_lin[wl * 16 + q * 4 + 1]
                   + hq[2] * w_lin[wl * 16 + q * 4 + 2]
                   + hq[3] * w_lin[wl * 16 + q * 4 + 3];
        part += __shfl_xor(part, 16, 64);
        part += __shfl_xor(part, 32, 64);
        if (q == 0) red[wl][bcol] = part;
    }
    __syncthreads();
    if (tid < 16) {
        float s = red[0][tid] + red[1][tid] + red[2][tid] + red[3][tid] + b_lin[0];
        out[b0 + tid] = rcp1p2(-s * LOG2E);
    }
}

extern "C" void kernel_launch(void* const* d_in, const int* in_sizes, int n_in,
                              void* d_out, int out_size, void* d_ws, size_t ws_size,
                              hipStream_t stream) {
    const float* x     = (const float*)d_in[0];
    const float* w_ih0 = (const float*)d_in[1];
    const float* w_hh0 = (const float*)d_in[2];
    const float* b_ih0 = (const float*)d_in[3];
    const float* b_hh0 = (const float*)d_in[4];
    const float* w_ih1 = (const float*)d_in[5];
    const float* w_hh1 = (const float*)d_in[6];
    const float* b_ih1 = (const float*)d_in[7];
    const float* b_hh1 = (const float*)d_in[8];
    const float* w_lin = (const float*)d_in[9];
    const float* b_lin = (const float*)d_in[10];

    lstm_fused<<<dim3(256), dim3(512), 0, stream>>>(
        x, w_ih0, w_hh0, b_ih0, b_hh0,
        w_ih1, w_hh1, b_ih1, b_hh1,
        w_lin, b_lin, (float*)d_out);
}